// Round 1
// baseline (4442.311 us; speedup 1.0000x reference)
//
#include <hip/hip_runtime.h>

#define SDIM 2048
#define DDIM 1024
#define NH 16
#define DK 64
#define NB 2
#define MROWS (NB * SDIM) // 4096

// ---------- shared helpers ----------

// Load a 64x64 fp32 tile (row stride DK) transposed into LDS [kk][row(+pad)]
__device__ __forceinline__ void load_tile_T(const float* __restrict__ src,
                                            float (*dst)[68], int t) {
  const int lr = t >> 2;          // 0..63 row
  const int lcb = (t & 3) * 4;    // 0,4,8,12
#pragma unroll
  for (int i = 0; i < 4; ++i) {
    int c = lcb + i * 16;
    float4 v = *(const float4*)&src[(size_t)lr * DK + c];
    dst[c + 0][lr] = v.x;
    dst[c + 1][lr] = v.y;
    dst[c + 2][lr] = v.z;
    dst[c + 3][lr] = v.w;
  }
}

// 64x64x64 fp32 score tile: sc[r][c] = 0.125 * sum_kk Qs[kk][ty4+r]*Ks[kk][tx4+c]
// Identical fmaf chain in pass1 and pass2 -> bitwise identical scores.
__device__ __forceinline__ void score_tile(const float (*Qs)[68],
                                           const float (*Ks)[68], int tx,
                                           int ty, float sc[4][4]) {
  float acc[4][4] = {};
#pragma unroll
  for (int kk = 0; kk < 64; ++kk) {
    float4 a4 = *(const float4*)&Qs[kk][ty * 4];
    float4 b4 = *(const float4*)&Ks[kk][tx * 4];
    const float a[4] = {a4.x, a4.y, a4.z, a4.w};
    const float b[4] = {b4.x, b4.y, b4.z, b4.w};
#pragma unroll
    for (int r = 0; r < 4; ++r)
#pragma unroll
      for (int c = 0; c < 4; ++c)
        acc[r][c] = fmaf(a[r], b[c], acc[r][c]);
  }
#pragma unroll
  for (int r = 0; r < 4; ++r)
#pragma unroll
    for (int c = 0; c < 4; ++c)
      sc[r][c] = acc[r][c] * 0.125f;
}

// ---------- K1: QKV projection, out = x @ W^T + b, head-split layout ----------
// out[((b*NH+h)*SDIM + s)*DK + d]
__global__ __launch_bounds__(256) void qkv_gemm(const float* __restrict__ A,
                                                const float* __restrict__ W,
                                                const float* __restrict__ bias,
                                                float* __restrict__ out) {
  __shared__ float As[16][68];
  __shared__ float Ws[16][68];
  const int t = threadIdx.x;
  const int tx = t & 15, ty = t >> 4;
  const int m0 = blockIdx.y * 64;
  const int n0 = blockIdx.x * 64;
  const int lr = t >> 2;       // 0..63
  const int lc = (t & 3) * 4;  // 0,4,8,12
  float acc[4][4] = {};
  for (int k0 = 0; k0 < DDIM; k0 += 16) {
    __syncthreads();
    float4 av = *(const float4*)&A[(size_t)(m0 + lr) * DDIM + k0 + lc];
    float4 wv = *(const float4*)&W[(size_t)(n0 + lr) * DDIM + k0 + lc];
    As[lc + 0][lr] = av.x; As[lc + 1][lr] = av.y;
    As[lc + 2][lr] = av.z; As[lc + 3][lr] = av.w;
    Ws[lc + 0][lr] = wv.x; Ws[lc + 1][lr] = wv.y;
    Ws[lc + 2][lr] = wv.z; Ws[lc + 3][lr] = wv.w;
    __syncthreads();
#pragma unroll
    for (int kk = 0; kk < 16; ++kk) {
      float4 a4 = *(const float4*)&As[kk][ty * 4];
      float4 b4 = *(const float4*)&Ws[kk][tx * 4];
      const float a[4] = {a4.x, a4.y, a4.z, a4.w};
      const float b[4] = {b4.x, b4.y, b4.z, b4.w};
#pragma unroll
      for (int r = 0; r < 4; ++r)
#pragma unroll
        for (int c = 0; c < 4; ++c)
          acc[r][c] = fmaf(a[r], b[c], acc[r][c]);
    }
  }
  const int nb = n0 + tx * 4;
  const float4 bv = *(const float4*)&bias[nb];
  const int h = nb >> 6, d = nb & 63;
#pragma unroll
  for (int r = 0; r < 4; ++r) {
    int m = m0 + ty * 4 + r;
    int b = m >> 11, s = m & 2047;
    float4 o;
    o.x = acc[r][0] + bv.x;
    o.y = acc[r][1] + bv.y;
    o.z = acc[r][2] + bv.z;
    o.w = acc[r][3] + bv.w;
    *(float4*)&out[((size_t)(b * NH + h) * SDIM + s) * DK + d] = o;
  }
}

// ---------- K2: softmax stats (exact row max m, denom l) ----------
__global__ __launch_bounds__(256) void attn_stats(const float* __restrict__ Q,
                                                  const float* __restrict__ K,
                                                  float* __restrict__ mOut,
                                                  float* __restrict__ lOut) {
  const int t = threadIdx.x;
  const int tx = t & 15, ty = t >> 4;
  const int q0 = blockIdx.x * 64;
  const int bh = blockIdx.y;
  const float* Qh = Q + (size_t)bh * SDIM * DK;
  const float* Kh = K + (size_t)bh * SDIM * DK;
  __shared__ float Qs[64][68];
  __shared__ float Ks[64][68];
  __shared__ float red[64][17];
  __shared__ float mNew[64];

  load_tile_T(Qh + (size_t)q0 * DK, Qs, t);

  float mRun = -INFINITY, lRun = 0.f;  // valid for t<64 (row t)
  float m_old = -INFINITY, m_n = -INFINITY;

  for (int k0 = 0; k0 < SDIM; k0 += 64) {
    __syncthreads();  // protect Ks / red reuse
    load_tile_T(Kh + (size_t)k0 * DK, Ks, t);
    __syncthreads();

    float sc[4][4];
    score_tile(Qs, Ks, tx, ty, sc);

    // per-row tile max reduce
#pragma unroll
    for (int r = 0; r < 4; ++r) {
      float lm = fmaxf(fmaxf(sc[r][0], sc[r][1]), fmaxf(sc[r][2], sc[r][3]));
      red[ty * 4 + r][tx] = lm;
    }
    __syncthreads();
    if (t < 64) {
      float tm = red[t][0];
      for (int j = 1; j < 16; ++j) tm = fmaxf(tm, red[t][j]);
      m_old = mRun;
      m_n = fmaxf(m_old, tm);
      mNew[t] = m_n;
    }
    __syncthreads();
#pragma unroll
    for (int r = 0; r < 4; ++r) {
      int row = ty * 4 + r;
      float mn = mNew[row];
      float es = expf(sc[r][0] - mn) + expf(sc[r][1] - mn) +
                 expf(sc[r][2] - mn) + expf(sc[r][3] - mn);
      red[row][tx] = es;
    }
    __syncthreads();
    if (t < 64) {
      float ssum = 0.f;
      for (int j = 0; j < 16; ++j) ssum += red[t][j];
      lRun = lRun * expf(m_old - m_n) + ssum;
      mRun = m_n;
    }
  }
  if (t < 64) {
    mOut[(size_t)bh * SDIM + q0 + t] = mRun;
    lOut[(size_t)bh * SDIM + q0 + t] = lRun;
  }
}

// ---------- K3: probs, att_sum/att_mask, sparse ctx events ----------
__global__ __launch_bounds__(256) void attn_pass2(
    const float* __restrict__ Q, const float* __restrict__ K,
    const float* __restrict__ V, const float* __restrict__ mS,
    const float* __restrict__ lS, float* __restrict__ attSum,
    float* __restrict__ attMask, float* __restrict__ merged,
    int* __restrict__ flags) {
  const int t = threadIdx.x;
  const int tx = t & 15, ty = t >> 4;
  const int k0 = blockIdx.x * 64;
  const int q0 = blockIdx.y * 64;
  const int b = blockIdx.z;
  __shared__ float Qs[64][68];
  __shared__ float Ks[64][68];
  __shared__ float mL[64], ilL[64];

  float asum[4][4] = {};
  float amask[4][4] = {};

  for (int h = 0; h < NH; ++h) {
    const int bh = b * NH + h;
    const float* Qh = Q + (size_t)bh * SDIM * DK;
    const float* Kh = K + (size_t)bh * SDIM * DK;
    __syncthreads();
    load_tile_T(Qh + (size_t)q0 * DK, Qs, t);
    load_tile_T(Kh + (size_t)k0 * DK, Ks, t);
    if (t < 64) {
      mL[t] = mS[(size_t)bh * SDIM + q0 + t];
      ilL[t] = 1.0f / lS[(size_t)bh * SDIM + q0 + t];
    }
    __syncthreads();

    float sc[4][4];
    score_tile(Qs, Ks, tx, ty, sc);

#pragma unroll
    for (int r = 0; r < 4; ++r) {
      const int row = ty * 4 + r;
      const int qrow = q0 + row;
      const float mn = mL[row];
      const float il = ilL[row];
#pragma unroll
      for (int c = 0; c < 4; ++c) {
        float p = expf(sc[r][c] - mn) * il;
        asum[r][c] += p;
        if (p >= 0.1f) {
          amask[r][c] += 1.0f;
          const int krow = k0 + tx * 4 + c;
          const float* vr = V + ((size_t)bh * SDIM + krow) * DK;
          float* mr = merged + ((size_t)(b * SDIM) + qrow) * DDIM + h * DK;
          for (int d = 0; d < DK; ++d) atomicAdd(&mr[d], p * vr[d]);
          flags[b * SDIM + qrow] = 1;
        }
      }
    }
  }
#pragma unroll
  for (int r = 0; r < 4; ++r) {
    size_t dst = ((size_t)(b * SDIM) + q0 + ty * 4 + r) * SDIM + k0 + tx * 4;
    float4 s4 = {asum[r][0], asum[r][1], asum[r][2], asum[r][3]};
    float4 m4 = {amask[r][0], amask[r][1], amask[r][2], amask[r][3]};
    *(float4*)&attSum[dst] = s4;
    *(float4*)&attMask[dst] = m4;
  }
}

// ---------- K4: output projection with all-zero-row-tile skip ----------
__global__ __launch_bounds__(256) void out_gemm(const float* __restrict__ A,
                                                const float* __restrict__ W,
                                                const float* __restrict__ bias,
                                                float* __restrict__ out,
                                                const int* __restrict__ flags) {
  __shared__ float As[16][68];
  __shared__ float Ws[16][68];
  __shared__ int anyF;
  const int t = threadIdx.x;
  const int tx = t & 15, ty = t >> 4;
  const int m0 = blockIdx.y * 64;
  const int n0 = blockIdx.x * 64;
  if (t == 0) anyF = 0;
  __syncthreads();
  if (t < 64 && flags[m0 + t]) anyF = 1;
  __syncthreads();
  const int nb = n0 + tx * 4;
  const float4 bv = *(const float4*)&bias[nb];
  if (!anyF) {
#pragma unroll
    for (int r = 0; r < 4; ++r)
      *(float4*)&out[(size_t)(m0 + ty * 4 + r) * DDIM + nb] = bv;
    return;
  }
  const int lr = t >> 2;
  const int lc = (t & 3) * 4;
  float acc[4][4] = {};
  for (int k0 = 0; k0 < DDIM; k0 += 16) {
    __syncthreads();
    float4 av = *(const float4*)&A[(size_t)(m0 + lr) * DDIM + k0 + lc];
    float4 wv = *(const float4*)&W[(size_t)(n0 + lr) * DDIM + k0 + lc];
    As[lc + 0][lr] = av.x; As[lc + 1][lr] = av.y;
    As[lc + 2][lr] = av.z; As[lc + 3][lr] = av.w;
    Ws[lc + 0][lr] = wv.x; Ws[lc + 1][lr] = wv.y;
    Ws[lc + 2][lr] = wv.z; Ws[lc + 3][lr] = wv.w;
    __syncthreads();
#pragma unroll
    for (int kk = 0; kk < 16; ++kk) {
      float4 a4 = *(const float4*)&As[kk][ty * 4];
      float4 b4 = *(const float4*)&Ws[kk][tx * 4];
      const float a[4] = {a4.x, a4.y, a4.z, a4.w};
      const float b[4] = {b4.x, b4.y, b4.z, b4.w};
#pragma unroll
      for (int r = 0; r < 4; ++r)
#pragma unroll
        for (int c = 0; c < 4; ++c)
          acc[r][c] = fmaf(a[r], b[c], acc[r][c]);
    }
  }
#pragma unroll
  for (int r = 0; r < 4; ++r) {
    float4 o;
    o.x = acc[r][0] + bv.x;
    o.y = acc[r][1] + bv.y;
    o.z = acc[r][2] + bv.z;
    o.w = acc[r][3] + bv.w;
    *(float4*)&out[(size_t)(m0 + ty * 4 + r) * DDIM + nb] = o;
  }
}

// ---------- launcher ----------
extern "C" void kernel_launch(void* const* d_in, const int* in_sizes, int n_in,
                              void* d_out, int out_size, void* d_ws,
                              size_t ws_size, hipStream_t stream) {
  const float* x = (const float*)d_in[0];
  const float* Wq = (const float*)d_in[1];
  const float* bq = (const float*)d_in[2];
  const float* Wk = (const float*)d_in[3];
  const float* bk = (const float*)d_in[4];
  const float* Wv = (const float*)d_in[5];
  const float* bv = (const float*)d_in[6];
  const float* Wo = (const float*)d_in[7];
  const float* bo = (const float*)d_in[8];

  float* out = (float*)d_out;
  float* attSum = out + (size_t)MROWS * DDIM;            // 4,194,304
  float* attMask = attSum + (size_t)NB * SDIM * SDIM;    // +8,388,608

  char* ws = (char*)d_ws;
  const size_t big = (size_t)MROWS * DDIM * sizeof(float);  // 16.78 MB
  float* Q = (float*)ws;            ws += big;
  float* K = (float*)ws;            ws += big;
  float* V = (float*)ws;            ws += big;
  float* merged = (float*)ws;       ws += big;
  float* mS = (float*)ws;           ws += (size_t)NB * NH * SDIM * sizeof(float);
  float* lS = (float*)ws;           ws += (size_t)NB * NH * SDIM * sizeof(float);
  int* flags = (int*)ws;            ws += (size_t)MROWS * sizeof(int);

  hipMemsetAsync(merged, 0, big, stream);
  hipMemsetAsync(flags, 0, (size_t)MROWS * sizeof(int), stream);

  dim3 blk(256);
  qkv_gemm<<<dim3(16, 64), blk, 0, stream>>>(x, Wq, bq, Q);
  qkv_gemm<<<dim3(16, 64), blk, 0, stream>>>(x, Wk, bk, K);
  qkv_gemm<<<dim3(16, 64), blk, 0, stream>>>(x, Wv, bv, V);
  attn_stats<<<dim3(32, 32), blk, 0, stream>>>(Q, K, mS, lS);
  attn_pass2<<<dim3(32, 32, 2), blk, 0, stream>>>(Q, K, V, mS, lS, attSum,
                                                  attMask, merged, flags);
  out_gemm<<<dim3(16, 64), blk, 0, stream>>>(merged, Wo, bo, out, flags);
}

// Round 2
// 598.714 us; speedup vs baseline: 7.4198x; 7.4198x over previous
//
#include <hip/hip_runtime.h>

#define SDIM 2048
#define DDIM 1024
#define NH 16
#define DK 64
#define NB 2
#define MROWS (NB * SDIM) // 4096
#define MAXEV 65536

typedef _Float16 f16x8 __attribute__((ext_vector_type(8)));
typedef _Float16 f16x4 __attribute__((ext_vector_type(4)));
typedef float f32x4 __attribute__((ext_vector_type(4)));

// ---------- K1a: QKV projection fp32 out (V), out = x @ W^T + b, head-split ----------
__global__ __launch_bounds__(256) void qkv_gemm(const float* __restrict__ A,
                                                const float* __restrict__ W,
                                                const float* __restrict__ bias,
                                                float* __restrict__ out) {
  __shared__ float As[16][68];
  __shared__ float Ws[16][68];
  const int t = threadIdx.x;
  const int tx = t & 15, ty = t >> 4;
  const int m0 = blockIdx.y * 64;
  const int n0 = blockIdx.x * 64;
  const int lr = t >> 2;
  const int lc = (t & 3) * 4;
  float acc[4][4] = {};
  for (int k0 = 0; k0 < DDIM; k0 += 16) {
    __syncthreads();
    float4 av = *(const float4*)&A[(size_t)(m0 + lr) * DDIM + k0 + lc];
    float4 wv = *(const float4*)&W[(size_t)(n0 + lr) * DDIM + k0 + lc];
    As[lc + 0][lr] = av.x; As[lc + 1][lr] = av.y;
    As[lc + 2][lr] = av.z; As[lc + 3][lr] = av.w;
    Ws[lc + 0][lr] = wv.x; Ws[lc + 1][lr] = wv.y;
    Ws[lc + 2][lr] = wv.z; Ws[lc + 3][lr] = wv.w;
    __syncthreads();
#pragma unroll
    for (int kk = 0; kk < 16; ++kk) {
      float4 a4 = *(const float4*)&As[kk][ty * 4];
      float4 b4 = *(const float4*)&Ws[kk][tx * 4];
      const float a[4] = {a4.x, a4.y, a4.z, a4.w};
      const float b[4] = {b4.x, b4.y, b4.z, b4.w};
#pragma unroll
      for (int r = 0; r < 4; ++r)
#pragma unroll
        for (int c = 0; c < 4; ++c)
          acc[r][c] = fmaf(a[r], b[c], acc[r][c]);
    }
  }
  const int nb = n0 + tx * 4;
  const float4 bv = *(const float4*)&bias[nb];
  const int h = nb >> 6, d = nb & 63;
#pragma unroll
  for (int r = 0; r < 4; ++r) {
    int m = m0 + ty * 4 + r;
    int b = m >> 11, s = m & 2047;
    float4 o;
    o.x = acc[r][0] + bv.x;
    o.y = acc[r][1] + bv.y;
    o.z = acc[r][2] + bv.z;
    o.w = acc[r][3] + bv.w;
    *(float4*)&out[((size_t)(b * NH + h) * SDIM + s) * DK + d] = o;
  }
}

// ---------- K1b: QKV projection fp16 out (Q,K) ----------
__global__ __launch_bounds__(256) void qkv_gemm_h(const float* __restrict__ A,
                                                  const float* __restrict__ W,
                                                  const float* __restrict__ bias,
                                                  _Float16* __restrict__ out) {
  __shared__ float As[16][68];
  __shared__ float Ws[16][68];
  const int t = threadIdx.x;
  const int tx = t & 15, ty = t >> 4;
  const int m0 = blockIdx.y * 64;
  const int n0 = blockIdx.x * 64;
  const int lr = t >> 2;
  const int lc = (t & 3) * 4;
  float acc[4][4] = {};
  for (int k0 = 0; k0 < DDIM; k0 += 16) {
    __syncthreads();
    float4 av = *(const float4*)&A[(size_t)(m0 + lr) * DDIM + k0 + lc];
    float4 wv = *(const float4*)&W[(size_t)(n0 + lr) * DDIM + k0 + lc];
    As[lc + 0][lr] = av.x; As[lc + 1][lr] = av.y;
    As[lc + 2][lr] = av.z; As[lc + 3][lr] = av.w;
    Ws[lc + 0][lr] = wv.x; Ws[lc + 1][lr] = wv.y;
    Ws[lc + 2][lr] = wv.z; Ws[lc + 3][lr] = wv.w;
    __syncthreads();
#pragma unroll
    for (int kk = 0; kk < 16; ++kk) {
      float4 a4 = *(const float4*)&As[kk][ty * 4];
      float4 b4 = *(const float4*)&Ws[kk][tx * 4];
      const float a[4] = {a4.x, a4.y, a4.z, a4.w};
      const float b[4] = {b4.x, b4.y, b4.z, b4.w};
#pragma unroll
      for (int r = 0; r < 4; ++r)
#pragma unroll
        for (int c = 0; c < 4; ++c)
          acc[r][c] = fmaf(a[r], b[c], acc[r][c]);
    }
  }
  const int nb = n0 + tx * 4;
  const float4 bv = *(const float4*)&bias[nb];
  const int h = nb >> 6, d = nb & 63;
#pragma unroll
  for (int r = 0; r < 4; ++r) {
    int m = m0 + ty * 4 + r;
    int b = m >> 11, s = m & 2047;
    f16x4 o;
    o[0] = (_Float16)(acc[r][0] + bv.x);
    o[1] = (_Float16)(acc[r][1] + bv.y);
    o[2] = (_Float16)(acc[r][2] + bv.z);
    o[3] = (_Float16)(acc[r][3] + bv.w);
    *(f16x4*)&out[((size_t)(b * NH + h) * SDIM + s) * DK + d] = o;
  }
}

// ---------- K2: row denominators l = sum_k exp(s) (no max subtraction; |s|<~7) ----------
__global__ __launch_bounds__(256) void attn_denom(const _Float16* __restrict__ Q,
                                                  const _Float16* __restrict__ K,
                                                  float* __restrict__ invDen) {
  __shared__ _Float16 Ks[64 * 72]; // row stride 72 halfs (144B): 16B-aligned, 2-way banks
  const int t = threadIdx.x;
  const int lane = t & 63, wave = t >> 6;
  const int quad = lane >> 4, lr = lane & 15;
  const int q0 = blockIdx.x * 64;
  const int bh = blockIdx.y;
  const _Float16* Qh = Q + (size_t)bh * SDIM * DK;
  const _Float16* Kh = K + (size_t)bh * SDIM * DK;
  // A-frags: A[m=lane&15][k=quad*8+j], rows = wave's 16-row strip
  const size_t qoff = (size_t)(q0 + wave * 16 + lr) * DK + quad * 8;
  f16x8 aq0 = *(const f16x8*)&Qh[qoff];
  f16x8 aq1 = *(const f16x8*)&Qh[qoff + 32];
  float dsum[4] = {0.f, 0.f, 0.f, 0.f};
  const int srow = t >> 2, scol = (t & 3) * 16;
  for (int k0 = 0; k0 < SDIM; k0 += 64) {
    __syncthreads();
    *(f16x8*)&Ks[srow * 72 + scol] =
        *(const f16x8*)&Kh[(size_t)(k0 + srow) * DK + scol];
    *(f16x8*)&Ks[srow * 72 + scol + 8] =
        *(const f16x8*)&Kh[(size_t)(k0 + srow) * DK + scol + 8];
    __syncthreads();
#pragma unroll
    for (int c = 0; c < 4; ++c) {
      f16x8 b0 = *(const f16x8*)&Ks[(c * 16 + lr) * 72 + quad * 8];
      f16x8 b1 = *(const f16x8*)&Ks[(c * 16 + lr) * 72 + 32 + quad * 8];
      f32x4 acc = {0.f, 0.f, 0.f, 0.f};
      acc = __builtin_amdgcn_mfma_f32_16x16x32_f16(aq0, b0, acc, 0, 0, 0);
      acc = __builtin_amdgcn_mfma_f32_16x16x32_f16(aq1, b1, acc, 0, 0, 0);
#pragma unroll
      for (int r = 0; r < 4; ++r)
        dsum[r] += __expf(acc[r] * 0.125f);
    }
  }
  // reduce over the 16 cols (low 4 lane bits)
#pragma unroll
  for (int m = 1; m < 16; m <<= 1)
#pragma unroll
    for (int r = 0; r < 4; ++r)
      dsum[r] += __shfl_xor(dsum[r], m, 64);
  if (lr == 0) {
#pragma unroll
    for (int r = 0; r < 4; ++r)
      invDen[(size_t)bh * SDIM + q0 + wave * 16 + quad * 4 + r] =
          1.0f / dsum[r];
  }
}

// ---------- K3: probs -> att_sum/att_mask dense; rare p>=0.1 -> event buffer ----------
__global__ __launch_bounds__(256) void attn_pass2(
    const _Float16* __restrict__ Q, const _Float16* __restrict__ K,
    const float* __restrict__ invDen, float* __restrict__ attSum,
    float* __restrict__ attMask, float4* __restrict__ ev,
    int* __restrict__ ecnt) {
  __shared__ float Tbuf[64 * 68]; // also aliased as half[64*72] for K staging
  _Float16* Ks = (_Float16*)Tbuf;
  const int t = threadIdx.x;
  const int lane = t & 63, wave = t >> 6;
  const int quad = lane >> 4, lr = lane & 15;
  const int k0 = blockIdx.x * 64;
  const int q0 = blockIdx.y * 64;
  const int b = blockIdx.z;
  const int srow = t >> 2, scol = (t & 3) * 16;
  float asum[4][4] = {};
  float amask[4][4] = {};
#pragma unroll 1
  for (int h = 0; h < NH; ++h) {
    const int bh = b * NH + h;
    const _Float16* Qh = Q + (size_t)bh * SDIM * DK;
    const _Float16* Kh = K + (size_t)bh * SDIM * DK;
    const size_t qoff = (size_t)(q0 + wave * 16 + lr) * DK + quad * 8;
    f16x8 aq0 = *(const f16x8*)&Qh[qoff];
    f16x8 aq1 = *(const f16x8*)&Qh[qoff + 32];
    float il[4];
#pragma unroll
    for (int r = 0; r < 4; ++r)
      il[r] = invDen[(size_t)bh * SDIM + q0 + wave * 16 + quad * 4 + r];
    __syncthreads(); // prev head's Ks reads done
    *(f16x8*)&Ks[srow * 72 + scol] =
        *(const f16x8*)&Kh[(size_t)(k0 + srow) * DK + scol];
    *(f16x8*)&Ks[srow * 72 + scol + 8] =
        *(const f16x8*)&Kh[(size_t)(k0 + srow) * DK + scol + 8];
    __syncthreads();
#pragma unroll
    for (int c = 0; c < 4; ++c) {
      f16x8 b0 = *(const f16x8*)&Ks[(c * 16 + lr) * 72 + quad * 8];
      f16x8 b1 = *(const f16x8*)&Ks[(c * 16 + lr) * 72 + 32 + quad * 8];
      f32x4 acc = {0.f, 0.f, 0.f, 0.f};
      acc = __builtin_amdgcn_mfma_f32_16x16x32_f16(aq0, b0, acc, 0, 0, 0);
      acc = __builtin_amdgcn_mfma_f32_16x16x32_f16(aq1, b1, acc, 0, 0, 0);
#pragma unroll
      for (int r = 0; r < 4; ++r) {
        float p = __expf(acc[r] * 0.125f) * il[r];
        asum[c][r] += p;
        if (p >= 0.1f) {
          amask[c][r] += 1.0f;
          int idx = atomicAdd(ecnt, 1);
          if (idx < MAXEV)
            ev[idx] = make_float4(
                __int_as_float(bh),
                __int_as_float(q0 + wave * 16 + quad * 4 + r),
                __int_as_float(k0 + c * 16 + lr), p);
        }
      }
    }
  }
  // epilogue: LDS transpose -> full-line float4 stores
  const int orow = t >> 2, ocol = (t & 3) * 16;
  __syncthreads();
#pragma unroll
  for (int c = 0; c < 4; ++c)
#pragma unroll
    for (int r = 0; r < 4; ++r)
      Tbuf[(wave * 16 + quad * 4 + r) * 68 + c * 16 + lr] = asum[c][r];
  __syncthreads();
#pragma unroll
  for (int j = 0; j < 4; ++j) {
    float4 v = *(float4*)&Tbuf[orow * 68 + ocol + j * 4];
    *(float4*)&attSum[((size_t)(b * SDIM) + q0 + orow) * SDIM + k0 + ocol +
                      j * 4] = v;
  }
  __syncthreads();
#pragma unroll
  for (int c = 0; c < 4; ++c)
#pragma unroll
    for (int r = 0; r < 4; ++r)
      Tbuf[(wave * 16 + quad * 4 + r) * 68 + c * 16 + lr] = amask[c][r];
  __syncthreads();
#pragma unroll
  for (int j = 0; j < 4; ++j) {
    float4 v = *(float4*)&Tbuf[orow * 68 + ocol + j * 4];
    *(float4*)&attMask[((size_t)(b * SDIM) + q0 + orow) * SDIM + k0 + ocol +
                       j * 4] = v;
  }
}

// ---------- K3b: apply rare events to merged ctx ----------
__global__ __launch_bounds__(64) void apply_events(
    const float4* __restrict__ ev, const int* __restrict__ ecnt,
    const float* __restrict__ V, float* __restrict__ merged,
    int* __restrict__ flags) {
  int n = *ecnt;
  if (n > MAXEV) n = MAXEV;
  const int d = threadIdx.x;
  for (int e = blockIdx.x; e < n; e += gridDim.x) {
    float4 r = ev[e];
    int bh = __float_as_int(r.x);
    int q = __float_as_int(r.y);
    int kc = __float_as_int(r.z);
    float p = r.w;
    int b = bh >> 4, h = bh & 15;
    atomicAdd(&merged[((size_t)(b * SDIM + q)) * DDIM + h * DK + d],
              p * V[((size_t)bh * SDIM + kc) * DK + d]);
    if (d == 0) flags[b * SDIM + q] = 1;
  }
}

// ---------- K4: output projection with all-zero-row-tile skip ----------
__global__ __launch_bounds__(256) void out_gemm(const float* __restrict__ A,
                                                const float* __restrict__ W,
                                                const float* __restrict__ bias,
                                                float* __restrict__ out,
                                                const int* __restrict__ flags) {
  __shared__ float As[16][68];
  __shared__ float Ws[16][68];
  __shared__ int anyF;
  const int t = threadIdx.x;
  const int tx = t & 15, ty = t >> 4;
  const int m0 = blockIdx.y * 64;
  const int n0 = blockIdx.x * 64;
  if (t == 0) anyF = 0;
  __syncthreads();
  if (t < 64 && flags[m0 + t]) anyF = 1;
  __syncthreads();
  const int nb = n0 + tx * 4;
  const float4 bv = *(const float4*)&bias[nb];
  if (!anyF) {
#pragma unroll
    for (int r = 0; r < 4; ++r)
      *(float4*)&out[(size_t)(m0 + ty * 4 + r) * DDIM + nb] = bv;
    return;
  }
  const int lr = t >> 2;
  const int lc = (t & 3) * 4;
  float acc[4][4] = {};
  for (int k0 = 0; k0 < DDIM; k0 += 16) {
    __syncthreads();
    float4 av = *(const float4*)&A[(size_t)(m0 + lr) * DDIM + k0 + lc];
    float4 wv = *(const float4*)&W[(size_t)(n0 + lr) * DDIM + k0 + lc];
    As[lc + 0][lr] = av.x; As[lc + 1][lr] = av.y;
    As[lc + 2][lr] = av.z; As[lc + 3][lr] = av.w;
    Ws[lc + 0][lr] = wv.x; Ws[lc + 1][lr] = wv.y;
    Ws[lc + 2][lr] = wv.z; Ws[lc + 3][lr] = wv.w;
    __syncthreads();
#pragma unroll
    for (int kk = 0; kk < 16; ++kk) {
      float4 a4 = *(const float4*)&As[kk][ty * 4];
      float4 b4 = *(const float4*)&Ws[kk][tx * 4];
      const float a[4] = {a4.x, a4.y, a4.z, a4.w};
      const float b[4] = {b4.x, b4.y, b4.z, b4.w};
#pragma unroll
      for (int r = 0; r < 4; ++r)
#pragma unroll
        for (int c = 0; c < 4; ++c)
          acc[r][c] = fmaf(a[r], b[c], acc[r][c]);
    }
  }
#pragma unroll
  for (int r = 0; r < 4; ++r) {
    float4 o;
    o.x = acc[r][0] + bv.x;
    o.y = acc[r][1] + bv.y;
    o.z = acc[r][2] + bv.z;
    o.w = acc[r][3] + bv.w;
    *(float4*)&out[(size_t)(m0 + ty * 4 + r) * DDIM + nb] = o;
  }
}

// ---------- launcher ----------
extern "C" void kernel_launch(void* const* d_in, const int* in_sizes, int n_in,
                              void* d_out, int out_size, void* d_ws,
                              size_t ws_size, hipStream_t stream) {
  const float* x = (const float*)d_in[0];
  const float* Wq = (const float*)d_in[1];
  const float* bq = (const float*)d_in[2];
  const float* Wk = (const float*)d_in[3];
  const float* bk = (const float*)d_in[4];
  const float* Wv = (const float*)d_in[5];
  const float* bv = (const float*)d_in[6];
  const float* Wo = (const float*)d_in[7];
  const float* bo = (const float*)d_in[8];

  float* out = (float*)d_out;
  float* attSum = out + (size_t)MROWS * DDIM;
  float* attMask = attSum + (size_t)NB * SDIM * SDIM;

  char* ws = (char*)d_ws;
  const size_t bigF = (size_t)MROWS * DDIM * sizeof(float);    // 16.78 MB
  const size_t bigH = (size_t)MROWS * DDIM * sizeof(_Float16); // 8.39 MB
  _Float16* Qh = (_Float16*)ws;  ws += bigH;
  _Float16* Kh = (_Float16*)ws;  ws += bigH;
  float* V = (float*)ws;         ws += bigF;
  float* merged = (float*)ws;    ws += bigF;
  float* invDen = (float*)ws;    ws += (size_t)NB * NH * SDIM * sizeof(float);
  float4* ev = (float4*)ws;      ws += (size_t)MAXEV * sizeof(float4);
  int* flags = (int*)ws;         ws += (size_t)MROWS * sizeof(int);
  int* ecnt = (int*)ws;          ws += 16;

  hipMemsetAsync(merged, 0, bigF, stream);
  hipMemsetAsync(flags, 0, (size_t)MROWS * sizeof(int), stream);
  hipMemsetAsync(ecnt, 0, 16, stream);

  dim3 blk(256);
  qkv_gemm_h<<<dim3(16, 64), blk, 0, stream>>>(x, Wq, bq, Qh);
  qkv_gemm_h<<<dim3(16, 64), blk, 0, stream>>>(x, Wk, bk, Kh);
  qkv_gemm<<<dim3(16, 64), blk, 0, stream>>>(x, Wv, bv, V);
  attn_denom<<<dim3(32, 32), blk, 0, stream>>>(Qh, Kh, invDen);
  attn_pass2<<<dim3(32, 32, 2), blk, 0, stream>>>(Qh, Kh, invDen, attSum,
                                                  attMask, ev, ecnt);
  apply_events<<<dim3(256), dim3(64), 0, stream>>>(ev, ecnt, V, merged, flags);
  out_gemm<<<dim3(16, 64), blk, 0, stream>>>(merged, Wo, bo, out, flags);
}

// Round 3
// 318.529 us; speedup vs baseline: 13.9463x; 1.8796x over previous
//
#include <hip/hip_runtime.h>

#define SDIM 2048
#define DDIM 1024
#define NH 16
#define DK 64
#define NB 2
#define MROWS (NB * SDIM) // 4096
#define MAXEV 65536

typedef _Float16 f16x8 __attribute__((ext_vector_type(8)));
typedef _Float16 f16x4 __attribute__((ext_vector_type(4)));
typedef float f32x4 __attribute__((ext_vector_type(4)));

__device__ __forceinline__ void ld_lds16(const _Float16* g, _Float16* l) {
  __builtin_amdgcn_global_load_lds(
      (const __attribute__((address_space(1))) void*)g,
      (__attribute__((address_space(3))) void*)l, 16, 0, 0);
}

// ---------- K0: fp32 -> fp16 (hi,lo) split ----------
__global__ __launch_bounds__(256) void split_f16(const float* __restrict__ src,
                                                 _Float16* __restrict__ hi,
                                                 _Float16* __restrict__ lo,
                                                 int n4) {
  int i = blockIdx.x * 256 + threadIdx.x;
  if (i >= n4) return;
  float4 v = ((const float4*)src)[i];
  f16x4 h, l;
  h[0] = (_Float16)v.x; l[0] = (_Float16)(v.x - (float)h[0]);
  h[1] = (_Float16)v.y; l[1] = (_Float16)(v.y - (float)h[1]);
  h[2] = (_Float16)v.z; l[2] = (_Float16)(v.z - (float)h[2]);
  h[3] = (_Float16)v.w; l[3] = (_Float16)(v.w - (float)h[3]);
  ((f16x4*)hi)[i] = h;
  ((f16x4*)lo)[i] = l;
}

// ---------- K1: fused QKV projection via split-fp16 MFMA ----------
// C = (Ah+Al) @ (Bh+Bl)^T + bias, 128x128 tile, BK=32, z selects Q/K/V.
__global__ __launch_bounds__(256, 3) void proj_gemm(
    const _Float16* __restrict__ xh, const _Float16* __restrict__ xl,
    const _Float16* __restrict__ Wqh, const _Float16* __restrict__ Wql,
    const _Float16* __restrict__ Wkh, const _Float16* __restrict__ Wkl,
    const _Float16* __restrict__ Wvh, const _Float16* __restrict__ Wvl,
    const float* __restrict__ bq, const float* __restrict__ bk,
    const float* __restrict__ bv, _Float16* __restrict__ Qo,
    _Float16* __restrict__ Ko, float* __restrict__ Vo) {
  __shared__ _Float16 sAh[128 * 32], sAl[128 * 32];
  __shared__ _Float16 sBh[128 * 32], sBl[128 * 32];
  const int t = threadIdx.x;
  const int lane = t & 63, wv = t >> 6;
  const int lr = lane & 15, quad = lane >> 4;
  const int wm = wv >> 1, wn = wv & 1;
  const int m0 = blockIdx.y * 128, n0 = blockIdx.x * 128;
  const int z = blockIdx.z;
  const _Float16* Bhp = z == 0 ? Wqh : (z == 1 ? Wkh : Wvh);
  const _Float16* Blp = z == 0 ? Wql : (z == 1 ? Wkl : Wvl);
  const float* bias = z == 0 ? bq : (z == 1 ? bk : bv);

  const int rb = wv * 32;                       // this wave's 32-row strip
  const int srow = lane >> 2, scol = (lane & 3) * 8;

  f32x4 acc[4][4];
#pragma unroll
  for (int i = 0; i < 4; ++i)
#pragma unroll
    for (int j = 0; j < 4; ++j) acc[i][j] = (f32x4){0.f, 0.f, 0.f, 0.f};

  for (int k0 = 0; k0 < DDIM; k0 += 32) {
    __syncthreads();  // prior LDS reads complete
#pragma unroll
    for (int j = 0; j < 32; j += 16) {
      const size_t ga = (size_t)(m0 + rb + j + srow) * DDIM + k0 + scol;
      const size_t gb = (size_t)(n0 + rb + j + srow) * DDIM + k0 + scol;
      ld_lds16(&xh[ga], &sAh[(rb + j) * 32]);
      ld_lds16(&xl[ga], &sAl[(rb + j) * 32]);
      ld_lds16(&Bhp[gb], &sBh[(rb + j) * 32]);
      ld_lds16(&Blp[gb], &sBl[(rb + j) * 32]);
    }
    __syncthreads();  // drains vmcnt(0): LDS data visible
    f16x8 ah[4], al[4], bh[4], bl[4];
#pragma unroll
    for (int i = 0; i < 4; ++i) {
      ah[i] = *(const f16x8*)&sAh[(wm * 64 + i * 16 + lr) * 32 + quad * 8];
      al[i] = *(const f16x8*)&sAl[(wm * 64 + i * 16 + lr) * 32 + quad * 8];
      bh[i] = *(const f16x8*)&sBh[(wn * 64 + i * 16 + lr) * 32 + quad * 8];
      bl[i] = *(const f16x8*)&sBl[(wn * 64 + i * 16 + lr) * 32 + quad * 8];
    }
#pragma unroll
    for (int i = 0; i < 4; ++i)
#pragma unroll
      for (int j = 0; j < 4; ++j) {
        acc[i][j] = __builtin_amdgcn_mfma_f32_16x16x32_f16(ah[i], bh[j],
                                                           acc[i][j], 0, 0, 0);
        acc[i][j] = __builtin_amdgcn_mfma_f32_16x16x32_f16(al[i], bh[j],
                                                           acc[i][j], 0, 0, 0);
        acc[i][j] = __builtin_amdgcn_mfma_f32_16x16x32_f16(ah[i], bl[j],
                                                           acc[i][j], 0, 0, 0);
      }
  }
  // epilogue: bias + head-split store (C layout: col=lane&15, row=quad*4+r)
#pragma unroll
  for (int j = 0; j < 4; ++j) {
    const int ng = n0 + wn * 64 + j * 16 + lr;
    const float bvv = bias[ng];
    const int h = ng >> 6, d = ng & 63;
#pragma unroll
    for (int i = 0; i < 4; ++i) {
#pragma unroll
      for (int r = 0; r < 4; ++r) {
        const int mg = m0 + wm * 64 + i * 16 + quad * 4 + r;
        const int b = mg >> 11, s = mg & 2047;
        const float o = acc[i][j][r] + bvv;
        const size_t off = ((size_t)(b * NH + h) * SDIM + s) * DK + d;
        if (z == 0)
          Qo[off] = (_Float16)o;
        else if (z == 1)
          Ko[off] = (_Float16)o;
        else
          Vo[off] = o;
      }
    }
  }
}

// ---------- K2: row denominators l = sum_k exp(s) (no max subtraction; |s|<~7) ----------
__global__ __launch_bounds__(256) void attn_denom(const _Float16* __restrict__ Q,
                                                  const _Float16* __restrict__ K,
                                                  float* __restrict__ invDen) {
  __shared__ _Float16 Ks[64 * 72];
  const int t = threadIdx.x;
  const int lane = t & 63, wave = t >> 6;
  const int quad = lane >> 4, lr = lane & 15;
  const int q0 = blockIdx.x * 64;
  const int bh = blockIdx.y;
  const _Float16* Qh = Q + (size_t)bh * SDIM * DK;
  const _Float16* Kh = K + (size_t)bh * SDIM * DK;
  const size_t qoff = (size_t)(q0 + wave * 16 + lr) * DK + quad * 8;
  f16x8 aq0 = *(const f16x8*)&Qh[qoff];
  f16x8 aq1 = *(const f16x8*)&Qh[qoff + 32];
  float dsum[4] = {0.f, 0.f, 0.f, 0.f};
  const int srow = t >> 2, scol = (t & 3) * 16;
  for (int k0 = 0; k0 < SDIM; k0 += 64) {
    __syncthreads();
    *(f16x8*)&Ks[srow * 72 + scol] =
        *(const f16x8*)&Kh[(size_t)(k0 + srow) * DK + scol];
    *(f16x8*)&Ks[srow * 72 + scol + 8] =
        *(const f16x8*)&Kh[(size_t)(k0 + srow) * DK + scol + 8];
    __syncthreads();
#pragma unroll
    for (int c = 0; c < 4; ++c) {
      f16x8 b0 = *(const f16x8*)&Ks[(c * 16 + lr) * 72 + quad * 8];
      f16x8 b1 = *(const f16x8*)&Ks[(c * 16 + lr) * 72 + 32 + quad * 8];
      f32x4 acc = {0.f, 0.f, 0.f, 0.f};
      acc = __builtin_amdgcn_mfma_f32_16x16x32_f16(aq0, b0, acc, 0, 0, 0);
      acc = __builtin_amdgcn_mfma_f32_16x16x32_f16(aq1, b1, acc, 0, 0, 0);
#pragma unroll
      for (int r = 0; r < 4; ++r)
        dsum[r] += __expf(acc[r] * 0.125f);
    }
  }
#pragma unroll
  for (int m = 1; m < 16; m <<= 1)
#pragma unroll
    for (int r = 0; r < 4; ++r)
      dsum[r] += __shfl_xor(dsum[r], m, 64);
  if (lr == 0) {
#pragma unroll
    for (int r = 0; r < 4; ++r)
      invDen[(size_t)bh * SDIM + q0 + wave * 16 + quad * 4 + r] =
          1.0f / dsum[r];
  }
}

// ---------- K3: probs -> att_sum/att_mask dense; rare p>=0.1 -> event buffer ----------
__global__ __launch_bounds__(256) void attn_pass2(
    const _Float16* __restrict__ Q, const _Float16* __restrict__ K,
    const float* __restrict__ invDen, float* __restrict__ attSum,
    float* __restrict__ attMask, float4* __restrict__ ev,
    int* __restrict__ ecnt) {
  __shared__ float Tbuf[64 * 68];
  _Float16* Ks = (_Float16*)Tbuf;
  const int t = threadIdx.x;
  const int lane = t & 63, wave = t >> 6;
  const int quad = lane >> 4, lr = lane & 15;
  const int k0 = blockIdx.x * 64;
  const int q0 = blockIdx.y * 64;
  const int b = blockIdx.z;
  const int srow = t >> 2, scol = (t & 3) * 16;
  float asum[4][4] = {};
  float amask[4][4] = {};
#pragma unroll 1
  for (int h = 0; h < NH; ++h) {
    const int bh = b * NH + h;
    const _Float16* Qh = Q + (size_t)bh * SDIM * DK;
    const _Float16* Kh = K + (size_t)bh * SDIM * DK;
    const size_t qoff = (size_t)(q0 + wave * 16 + lr) * DK + quad * 8;
    f16x8 aq0 = *(const f16x8*)&Qh[qoff];
    f16x8 aq1 = *(const f16x8*)&Qh[qoff + 32];
    float il[4];
#pragma unroll
    for (int r = 0; r < 4; ++r)
      il[r] = invDen[(size_t)bh * SDIM + q0 + wave * 16 + quad * 4 + r];
    __syncthreads();
    *(f16x8*)&Ks[srow * 72 + scol] =
        *(const f16x8*)&Kh[(size_t)(k0 + srow) * DK + scol];
    *(f16x8*)&Ks[srow * 72 + scol + 8] =
        *(const f16x8*)&Kh[(size_t)(k0 + srow) * DK + scol + 8];
    __syncthreads();
#pragma unroll
    for (int c = 0; c < 4; ++c) {
      f16x8 b0 = *(const f16x8*)&Ks[(c * 16 + lr) * 72 + quad * 8];
      f16x8 b1 = *(const f16x8*)&Ks[(c * 16 + lr) * 72 + 32 + quad * 8];
      f32x4 acc = {0.f, 0.f, 0.f, 0.f};
      acc = __builtin_amdgcn_mfma_f32_16x16x32_f16(aq0, b0, acc, 0, 0, 0);
      acc = __builtin_amdgcn_mfma_f32_16x16x32_f16(aq1, b1, acc, 0, 0, 0);
#pragma unroll
      for (int r = 0; r < 4; ++r) {
        float p = __expf(acc[r] * 0.125f) * il[r];
        asum[c][r] += p;
        if (p >= 0.1f) {
          amask[c][r] += 1.0f;
          int idx = atomicAdd(ecnt, 1);
          if (idx < MAXEV)
            ev[idx] = make_float4(
                __int_as_float(bh),
                __int_as_float(q0 + wave * 16 + quad * 4 + r),
                __int_as_float(k0 + c * 16 + lr), p);
        }
      }
    }
  }
  const int orow = t >> 2, ocol = (t & 3) * 16;
  __syncthreads();
#pragma unroll
  for (int c = 0; c < 4; ++c)
#pragma unroll
    for (int r = 0; r < 4; ++r)
      Tbuf[(wave * 16 + quad * 4 + r) * 68 + c * 16 + lr] = asum[c][r];
  __syncthreads();
#pragma unroll
  for (int j = 0; j < 4; ++j) {
    float4 v = *(float4*)&Tbuf[orow * 68 + ocol + j * 4];
    *(float4*)&attSum[((size_t)(b * SDIM) + q0 + orow) * SDIM + k0 + ocol +
                      j * 4] = v;
  }
  __syncthreads();
#pragma unroll
  for (int c = 0; c < 4; ++c)
#pragma unroll
    for (int r = 0; r < 4; ++r)
      Tbuf[(wave * 16 + quad * 4 + r) * 68 + c * 16 + lr] = amask[c][r];
  __syncthreads();
#pragma unroll
  for (int j = 0; j < 4; ++j) {
    float4 v = *(float4*)&Tbuf[orow * 68 + ocol + j * 4];
    *(float4*)&attMask[((size_t)(b * SDIM) + q0 + orow) * SDIM + k0 + ocol +
                       j * 4] = v;
  }
}

// ---------- K3b: apply rare events to merged ctx ----------
__global__ __launch_bounds__(64) void apply_events(
    const float4* __restrict__ ev, const int* __restrict__ ecnt,
    const float* __restrict__ V, float* __restrict__ merged,
    int* __restrict__ flags) {
  int n = *ecnt;
  if (n > MAXEV) n = MAXEV;
  const int d = threadIdx.x;
  for (int e = blockIdx.x; e < n; e += gridDim.x) {
    float4 r = ev[e];
    int bh = __float_as_int(r.x);
    int q = __float_as_int(r.y);
    int kc = __float_as_int(r.z);
    float p = r.w;
    int b = bh >> 4, h = bh & 15;
    atomicAdd(&merged[((size_t)(b * SDIM + q)) * DDIM + h * DK + d],
              p * V[((size_t)bh * SDIM + kc) * DK + d]);
    if (d == 0) flags[b * SDIM + q] = 1;
  }
}

// ---------- K4: output projection with all-zero-row-tile skip ----------
__global__ __launch_bounds__(256) void out_gemm(const float* __restrict__ A,
                                                const float* __restrict__ W,
                                                const float* __restrict__ bias,
                                                float* __restrict__ out,
                                                const int* __restrict__ flags) {
  __shared__ float As[16][68];
  __shared__ float Ws[16][68];
  __shared__ int anyF;
  const int t = threadIdx.x;
  const int tx = t & 15, ty = t >> 4;
  const int m0 = blockIdx.y * 64;
  const int n0 = blockIdx.x * 64;
  if (t == 0) anyF = 0;
  __syncthreads();
  if (t < 64 && flags[m0 + t]) anyF = 1;
  __syncthreads();
  const int nb = n0 + tx * 4;
  const float4 bv = *(const float4*)&bias[nb];
  if (!anyF) {
#pragma unroll
    for (int r = 0; r < 4; ++r)
      *(float4*)&out[(size_t)(m0 + ty * 4 + r) * DDIM + nb] = bv;
    return;
  }
  const int lr = t >> 2;
  const int lc = (t & 3) * 4;
  float acc[4][4] = {};
  for (int k0 = 0; k0 < DDIM; k0 += 16) {
    __syncthreads();
    float4 av = *(const float4*)&A[(size_t)(m0 + lr) * DDIM + k0 + lc];
    float4 wv = *(const float4*)&W[(size_t)(n0 + lr) * DDIM + k0 + lc];
    As[lc + 0][lr] = av.x; As[lc + 1][lr] = av.y;
    As[lc + 2][lr] = av.z; As[lc + 3][lr] = av.w;
    Ws[lc + 0][lr] = wv.x; Ws[lc + 1][lr] = wv.y;
    Ws[lc + 2][lr] = wv.z; Ws[lc + 3][lr] = wv.w;
    __syncthreads();
#pragma unroll
    for (int kk = 0; kk < 16; ++kk) {
      float4 a4 = *(const float4*)&As[kk][ty * 4];
      float4 b4 = *(const float4*)&Ws[kk][tx * 4];
      const float a[4] = {a4.x, a4.y, a4.z, a4.w};
      const float b[4] = {b4.x, b4.y, b4.z, b4.w};
#pragma unroll
      for (int r = 0; r < 4; ++r)
#pragma unroll
        for (int c = 0; c < 4; ++c)
          acc[r][c] = fmaf(a[r], b[c], acc[r][c]);
    }
  }
#pragma unroll
  for (int r = 0; r < 4; ++r) {
    float4 o;
    o.x = acc[r][0] + bv.x;
    o.y = acc[r][1] + bv.y;
    o.z = acc[r][2] + bv.z;
    o.w = acc[r][3] + bv.w;
    *(float4*)&out[(size_t)(m0 + ty * 4 + r) * DDIM + nb] = o;
  }
}

// ---------- launcher ----------
extern "C" void kernel_launch(void* const* d_in, const int* in_sizes, int n_in,
                              void* d_out, int out_size, void* d_ws,
                              size_t ws_size, hipStream_t stream) {
  const float* x = (const float*)d_in[0];
  const float* Wq = (const float*)d_in[1];
  const float* bq = (const float*)d_in[2];
  const float* Wk = (const float*)d_in[3];
  const float* bk = (const float*)d_in[4];
  const float* Wv = (const float*)d_in[5];
  const float* bv = (const float*)d_in[6];
  const float* Wo = (const float*)d_in[7];
  const float* bo = (const float*)d_in[8];

  float* out = (float*)d_out;
  float* attSum = out + (size_t)MROWS * DDIM;
  float* attMask = attSum + (size_t)NB * SDIM * SDIM;

  char* ws = (char*)d_ws;
  const size_t bigF = (size_t)MROWS * DDIM * sizeof(float);    // 16.78 MB
  const size_t bigH = (size_t)MROWS * DDIM * sizeof(_Float16); // 8.39 MB
  const size_t wH = (size_t)DDIM * DDIM * sizeof(_Float16);    // 2.10 MB
  _Float16* Qh = (_Float16*)ws;  ws += bigH;
  _Float16* Kh = (_Float16*)ws;  ws += bigH;
  float* V = (float*)ws;         ws += bigF;
  float* merged = (float*)ws;    ws += bigF;
  _Float16* xh = (_Float16*)ws;  ws += bigH;
  _Float16* xl = (_Float16*)ws;  ws += bigH;
  _Float16* Wqh = (_Float16*)ws; ws += wH;
  _Float16* Wql = (_Float16*)ws; ws += wH;
  _Float16* Wkh = (_Float16*)ws; ws += wH;
  _Float16* Wkl = (_Float16*)ws; ws += wH;
  _Float16* Wvh = (_Float16*)ws; ws += wH;
  _Float16* Wvl = (_Float16*)ws; ws += wH;
  float* invDen = (float*)ws;    ws += (size_t)NB * NH * SDIM * sizeof(float);
  float4* ev = (float4*)ws;      ws += (size_t)MAXEV * sizeof(float4);
  int* flags = (int*)ws;         ws += (size_t)MROWS * sizeof(int);
  int* ecnt = (int*)ws;          ws += 16;

  hipMemsetAsync(merged, 0, bigF, stream);
  hipMemsetAsync(flags, 0, (size_t)MROWS * sizeof(int), stream);
  hipMemsetAsync(ecnt, 0, 16, stream);

  dim3 blk(256);
  split_f16<<<dim3(4096), blk, 0, stream>>>(x, xh, xl, MROWS * DDIM / 4);
  split_f16<<<dim3(1024), blk, 0, stream>>>(Wq, Wqh, Wql, DDIM * DDIM / 4);
  split_f16<<<dim3(1024), blk, 0, stream>>>(Wk, Wkh, Wkl, DDIM * DDIM / 4);
  split_f16<<<dim3(1024), blk, 0, stream>>>(Wv, Wvh, Wvl, DDIM * DDIM / 4);
  proj_gemm<<<dim3(8, 32, 3), blk, 0, stream>>>(xh, xl, Wqh, Wql, Wkh, Wkl,
                                                Wvh, Wvl, bq, bk, bv, Qh, Kh,
                                                V);
  attn_denom<<<dim3(32, 32), blk, 0, stream>>>(Qh, Kh, invDen);
  attn_pass2<<<dim3(32, 32, 2), blk, 0, stream>>>(Qh, Kh, invDen, attSum,
                                                  attMask, ev, ecnt);
  apply_events<<<dim3(256), dim3(64), 0, stream>>>(ev, ecnt, V, merged, flags);
  out_gemm<<<dim3(16, 64), blk, 0, stream>>>(merged, Wo, bo, out, flags);
}

// Round 4
// 288.958 us; speedup vs baseline: 15.3736x; 1.1023x over previous
//
#include <hip/hip_runtime.h>

#define SDIM 2048
#define DDIM 1024
#define NH 16
#define DK 64
#define NB 2
#define MROWS (NB * SDIM) // 4096
#define MAXEV 65536
#define EXPC 0.18033688011112f // 0.125 * log2(e)

typedef _Float16 f16x8 __attribute__((ext_vector_type(8)));
typedef _Float16 f16x4 __attribute__((ext_vector_type(4)));
typedef float f32x4 __attribute__((ext_vector_type(4)));

__device__ __forceinline__ void ld_lds16(const _Float16* g, _Float16* l) {
  __builtin_amdgcn_global_load_lds(
      (const __attribute__((address_space(1))) void*)g,
      (__attribute__((address_space(3))) void*)l, 16, 0, 0);
}

// ---------- K0: fp32 -> fp16 convert, all four arrays in one launch ----------
__global__ __launch_bounds__(256) void cvt_f16(
    const float* __restrict__ x, const float* __restrict__ wq,
    const float* __restrict__ wk, const float* __restrict__ wv,
    _Float16* __restrict__ xh, _Float16* __restrict__ wqh,
    _Float16* __restrict__ wkh, _Float16* __restrict__ wvh) {
  int i = blockIdx.x * 256 + threadIdx.x; // float4 index
  const float* src;
  _Float16* dst;
  int off;
  if (i < 1048576) {
    src = x; dst = xh; off = i;
  } else if (i < 1310720) {
    src = wq; dst = wqh; off = i - 1048576;
  } else if (i < 1572864) {
    src = wk; dst = wkh; off = i - 1310720;
  } else {
    src = wv; dst = wvh; off = i - 1572864;
  }
  float4 v = ((const float4*)src)[off];
  f16x4 h;
  h[0] = (_Float16)v.x; h[1] = (_Float16)v.y;
  h[2] = (_Float16)v.z; h[3] = (_Float16)v.w;
  ((f16x4*)dst)[off] = h;
}

// ---------- K1: fused QKV projection, plain fp16 MFMA, 128x128 tile, BK=64 ----------
__global__ __launch_bounds__(256, 2) void proj_gemm(
    const _Float16* __restrict__ xh, const _Float16* __restrict__ Wqh,
    const _Float16* __restrict__ Wkh, const _Float16* __restrict__ Wvh,
    const float* __restrict__ bq, const float* __restrict__ bk,
    const float* __restrict__ bv, _Float16* __restrict__ Qo,
    _Float16* __restrict__ Ko, float* __restrict__ Vo) {
  __shared__ _Float16 sA[128 * 64]; // 16KB, XOR-swizzled chunks
  __shared__ _Float16 sB[128 * 64];
  const int t = threadIdx.x;
  const int lane = t & 63, wv = t >> 6;
  const int lr = lane & 15, quad = lane >> 4;
  const int wm = wv >> 1, wn = wv & 1;
  const int m0 = blockIdx.y * 128, n0 = blockIdx.x * 128;
  const int z = blockIdx.z;
  const _Float16* Bp = z == 0 ? Wqh : (z == 1 ? Wkh : Wvh);
  const float* bias = z == 0 ? bq : (z == 1 ? bk : bv);

  const int strow = t >> 3;            // 0..31 per issue
  const int stchunk = t & 7;           // phys chunk
  const int stsrc = (stchunk ^ (strow & 7)) * 8; // src col (halfs)

  f32x4 acc[4][4];
#pragma unroll
  for (int i = 0; i < 4; ++i)
#pragma unroll
    for (int j = 0; j < 4; ++j) acc[i][j] = (f32x4){0.f, 0.f, 0.f, 0.f};

  for (int k0 = 0; k0 < DDIM; k0 += 64) {
    __syncthreads(); // prior LDS reads complete
#pragma unroll
    for (int i = 0; i < 4; ++i) {
      const int row = i * 32 + strow;
      ld_lds16(&xh[(size_t)(m0 + row) * DDIM + k0 + stsrc],
               &sA[row * 64 + stchunk * 8]);
      ld_lds16(&Bp[(size_t)(n0 + row) * DDIM + k0 + stsrc],
               &sB[row * 64 + stchunk * 8]);
    }
    __syncthreads(); // drains vmcnt: LDS visible
    f16x8 af[4][2], bf[4][2];
#pragma unroll
    for (int i = 0; i < 4; ++i)
#pragma unroll
      for (int kk = 0; kk < 2; ++kk) {
        const int ph = ((kk * 4 + quad) ^ (lr & 7)) * 8;
        af[i][kk] = *(const f16x8*)&sA[(wm * 64 + i * 16 + lr) * 64 + ph];
        bf[i][kk] = *(const f16x8*)&sB[(wn * 64 + i * 16 + lr) * 64 + ph];
      }
#pragma unroll
    for (int kk = 0; kk < 2; ++kk)
#pragma unroll
      for (int i = 0; i < 4; ++i)
#pragma unroll
        for (int j = 0; j < 4; ++j)
          acc[i][j] = __builtin_amdgcn_mfma_f32_16x16x32_f16(
              af[i][kk], bf[j][kk], acc[i][j], 0, 0, 0);
  }
  // epilogue: bias + head-split store (C layout: col=lane&15, row=quad*4+r)
#pragma unroll
  for (int j = 0; j < 4; ++j) {
    const int ng = n0 + wn * 64 + j * 16 + lr;
    const float bvv = bias[ng];
    const int h = ng >> 6, d = ng & 63;
#pragma unroll
    for (int i = 0; i < 4; ++i) {
#pragma unroll
      for (int r = 0; r < 4; ++r) {
        const int mg = m0 + wm * 64 + i * 16 + quad * 4 + r;
        const int b = mg >> 11, s = mg & 2047;
        const float o = acc[i][j][r] + bvv;
        const size_t off = ((size_t)(b * NH + h) * SDIM + s) * DK + d;
        if (z == 0)
          Qo[off] = (_Float16)o;
        else if (z == 1)
          Ko[off] = (_Float16)o;
        else
          Vo[off] = o;
      }
    }
  }
}

// ---------- K2: row denominators, double-buffered K staging ----------
__global__ __launch_bounds__(256) void attn_denom(const _Float16* __restrict__ Q,
                                                  const _Float16* __restrict__ K,
                                                  float* __restrict__ invDen) {
  __shared__ _Float16 Kbuf[2 * 64 * 64]; // 16KB, XOR-swizzled
  const int t = threadIdx.x;
  const int lane = t & 63, wave = t >> 6;
  const int quad = lane >> 4, lr = lane & 15;
  const int q0 = blockIdx.x * 64;
  const int bh = blockIdx.y;
  const _Float16* Qh = Q + (size_t)bh * SDIM * DK;
  const _Float16* Kh = K + (size_t)bh * SDIM * DK;
  const size_t qoff = (size_t)(q0 + wave * 16 + lr) * DK + quad * 8;
  const f16x8 aq0 = *(const f16x8*)&Qh[qoff];
  const f16x8 aq1 = *(const f16x8*)&Qh[qoff + 32];
  const int strow = t >> 3, stchunk = t & 7;
  const int stsrc = (stchunk ^ (strow & 7)) * 8;
  const int ph0 = (quad ^ (lr & 7)) * 8;
  const int ph1 = ((4 + quad) ^ (lr & 7)) * 8;

  float dsum[4] = {0.f, 0.f, 0.f, 0.f};
  // stage k-tile 0 into buf0
#pragma unroll
  for (int i = 0; i < 2; ++i)
    ld_lds16(&Kh[(size_t)(i * 32 + strow) * DK + stsrc],
             &Kbuf[(i * 32 + strow) * 64 + stchunk * 8]);

  for (int kt = 0; kt < 32; ++kt) {
    __syncthreads(); // buf[kt&1] ready; prior reads done
    if (kt + 1 < 32) {
      const int kn = (kt + 1) * 64;
      const int bsel = ((kt + 1) & 1) * 4096;
#pragma unroll
      for (int i = 0; i < 2; ++i)
        ld_lds16(&Kh[(size_t)(kn + i * 32 + strow) * DK + stsrc],
                 &Kbuf[bsel + (i * 32 + strow) * 64 + stchunk * 8]);
    }
    const _Float16* Ks = &Kbuf[(kt & 1) * 4096];
#pragma unroll
    for (int c = 0; c < 4; ++c) {
      f16x8 b0 = *(const f16x8*)&Ks[(c * 16 + lr) * 64 + ph0];
      f16x8 b1 = *(const f16x8*)&Ks[(c * 16 + lr) * 64 + ph1];
      f32x4 acc = {0.f, 0.f, 0.f, 0.f};
      acc = __builtin_amdgcn_mfma_f32_16x16x32_f16(aq0, b0, acc, 0, 0, 0);
      acc = __builtin_amdgcn_mfma_f32_16x16x32_f16(aq1, b1, acc, 0, 0, 0);
#pragma unroll
      for (int r = 0; r < 4; ++r)
        dsum[r] += exp2f(acc[r] * EXPC);
    }
  }
#pragma unroll
  for (int m = 1; m < 16; m <<= 1)
#pragma unroll
    for (int r = 0; r < 4; ++r)
      dsum[r] += __shfl_xor(dsum[r], m, 64);
  if (lr == 0) {
#pragma unroll
    for (int r = 0; r < 4; ++r)
      invDen[(size_t)bh * SDIM + q0 + wave * 16 + quad * 4 + r] =
          1.0f / dsum[r];
  }
}

// ---------- K3: probs -> att_sum/att_mask; rare p>=0.1 -> event buffer ----------
__global__ __launch_bounds__(256) void attn_pass2(
    const _Float16* __restrict__ Q, const _Float16* __restrict__ K,
    const float* __restrict__ invDen, float* __restrict__ attSum,
    float* __restrict__ attMask, float4* __restrict__ ev,
    int* __restrict__ ecnt) {
  __shared__ float Tbuf[64 * 68];        // 17.4KB; first 16KB = K double-buffer
  _Float16* Kbuf = (_Float16*)Tbuf;      // 2 x 4096 halfs
  const int t = threadIdx.x;
  const int lane = t & 63, wave = t >> 6;
  const int quad = lane >> 4, lr = lane & 15;
  const int k0 = blockIdx.x * 64;
  const int q0 = blockIdx.y * 64;
  const int b = blockIdx.z;
  const int strow = t >> 3, stchunk = t & 7;
  const int stsrc = (stchunk ^ (strow & 7)) * 8;
  const int ph0 = (quad ^ (lr & 7)) * 8;
  const int ph1 = ((4 + quad) ^ (lr & 7)) * 8;

  const size_t qbase = ((size_t)(b * NH) * SDIM + q0 + wave * 16 + lr) * DK;
  const size_t dbase = (size_t)(b * NH) * SDIM + q0 + wave * 16 + quad * 4;
  const size_t hstep = (size_t)SDIM * DK;

  float asum[4][4] = {};
  float amask[4][4] = {};

  // prefetch h=0: K tile + Q frags + invDen
  {
    const _Float16* Kh = K + (size_t)(b * NH) * hstep + (size_t)k0 * DK;
#pragma unroll
    for (int i = 0; i < 2; ++i)
      ld_lds16(&Kh[(size_t)(i * 32 + strow) * DK + stsrc],
               &Kbuf[(i * 32 + strow) * 64 + stchunk * 8]);
  }
  f16x8 aq0n = *(const f16x8*)&Q[qbase + quad * 8];
  f16x8 aq1n = *(const f16x8*)&Q[qbase + 32 + quad * 8];
  float4 iln = *(const float4*)&invDen[dbase];

#pragma unroll 1
  for (int h = 0; h < NH; ++h) {
    const f16x8 aq0 = aq0n, aq1 = aq1n;
    const float4 il4 = iln;
    __syncthreads(); // buf[h&1] staged (vmcnt drained); prior reads done
    if (h + 1 < NH) {
      const _Float16* Kn =
          K + (size_t)(b * NH + h + 1) * hstep + (size_t)k0 * DK;
      const int bsel = ((h + 1) & 1) * 4096;
#pragma unroll
      for (int i = 0; i < 2; ++i)
        ld_lds16(&Kn[(size_t)(i * 32 + strow) * DK + stsrc],
                 &Kbuf[bsel + (i * 32 + strow) * 64 + stchunk * 8]);
      aq0n = *(const f16x8*)&Q[qbase + (size_t)(h + 1) * hstep + quad * 8];
      aq1n = *(const f16x8*)&Q[qbase + (size_t)(h + 1) * hstep + 32 + quad * 8];
      iln = *(const float4*)&invDen[dbase + (size_t)(h + 1) * SDIM];
    }
    const _Float16* Ks = &Kbuf[(h & 1) * 4096];
    const float il[4] = {il4.x, il4.y, il4.z, il4.w};
#pragma unroll
    for (int c = 0; c < 4; ++c) {
      f16x8 b0 = *(const f16x8*)&Ks[(c * 16 + lr) * 64 + ph0];
      f16x8 b1 = *(const f16x8*)&Ks[(c * 16 + lr) * 64 + ph1];
      f32x4 acc = {0.f, 0.f, 0.f, 0.f};
      acc = __builtin_amdgcn_mfma_f32_16x16x32_f16(aq0, b0, acc, 0, 0, 0);
      acc = __builtin_amdgcn_mfma_f32_16x16x32_f16(aq1, b1, acc, 0, 0, 0);
#pragma unroll
      for (int r = 0; r < 4; ++r) {
        float p = exp2f(acc[r] * EXPC) * il[r];
        asum[c][r] += p;
        if (p >= 0.1f) {
          amask[c][r] += 1.0f;
          int idx = atomicAdd(ecnt, 1);
          if (idx < MAXEV)
            ev[idx] = make_float4(
                __int_as_float(b * NH + h),
                __int_as_float(q0 + wave * 16 + quad * 4 + r),
                __int_as_float(k0 + c * 16 + lr), p);
        }
      }
    }
  }
  // epilogue: LDS transpose -> full-line float4 stores
  const int orow = t >> 2, ocol = (t & 3) * 16;
  __syncthreads();
#pragma unroll
  for (int c = 0; c < 4; ++c)
#pragma unroll
    for (int r = 0; r < 4; ++r)
      Tbuf[(wave * 16 + quad * 4 + r) * 68 + c * 16 + lr] = asum[c][r];
  __syncthreads();
#pragma unroll
  for (int j = 0; j < 4; ++j) {
    float4 v = *(float4*)&Tbuf[orow * 68 + ocol + j * 4];
    *(float4*)&attSum[((size_t)(b * SDIM) + q0 + orow) * SDIM + k0 + ocol +
                      j * 4] = v;
  }
  __syncthreads();
#pragma unroll
  for (int c = 0; c < 4; ++c)
#pragma unroll
    for (int r = 0; r < 4; ++r)
      Tbuf[(wave * 16 + quad * 4 + r) * 68 + c * 16 + lr] = amask[c][r];
  __syncthreads();
#pragma unroll
  for (int j = 0; j < 4; ++j) {
    float4 v = *(float4*)&Tbuf[orow * 68 + ocol + j * 4];
    *(float4*)&attMask[((size_t)(b * SDIM) + q0 + orow) * SDIM + k0 + ocol +
                       j * 4] = v;
  }
}

// ---------- K3b: apply rare events to merged ctx ----------
__global__ __launch_bounds__(64) void apply_events(
    const float4* __restrict__ ev, const int* __restrict__ ecnt,
    const float* __restrict__ V, float* __restrict__ merged,
    int* __restrict__ flags) {
  int n = *ecnt;
  if (n > MAXEV) n = MAXEV;
  const int d = threadIdx.x;
  for (int e = blockIdx.x; e < n; e += gridDim.x) {
    float4 r = ev[e];
    int bh = __float_as_int(r.x);
    int q = __float_as_int(r.y);
    int kc = __float_as_int(r.z);
    float p = r.w;
    int b = bh >> 4, h = bh & 15;
    atomicAdd(&merged[((size_t)(b * SDIM + q)) * DDIM + h * DK + d],
              p * V[((size_t)bh * SDIM + kc) * DK + d]);
    if (d == 0) flags[b * SDIM + q] = 1;
  }
}

// ---------- K4: output projection with all-zero-row-tile skip ----------
__global__ __launch_bounds__(256) void out_gemm(const float* __restrict__ A,
                                                const float* __restrict__ W,
                                                const float* __restrict__ bias,
                                                float* __restrict__ out,
                                                const int* __restrict__ flags) {
  __shared__ float As[16][68];
  __shared__ float Ws[16][68];
  __shared__ int anyF;
  const int t = threadIdx.x;
  const int tx = t & 15, ty = t >> 4;
  const int m0 = blockIdx.y * 64;
  const int n0 = blockIdx.x * 64;
  if (t == 0) anyF = 0;
  __syncthreads();
  if (t < 64 && flags[m0 + t]) anyF = 1;
  __syncthreads();
  const int nb = n0 + tx * 4;
  const float4 bv = *(const float4*)&bias[nb];
  if (!anyF) {
#pragma unroll
    for (int r = 0; r < 4; ++r)
      *(float4*)&out[(size_t)(m0 + ty * 4 + r) * DDIM + nb] = bv;
    return;
  }
  const int lr = t >> 2;
  const int lc = (t & 3) * 4;
  float acc[4][4] = {};
  for (int k0 = 0; k0 < DDIM; k0 += 16) {
    __syncthreads();
    float4 av = *(const float4*)&A[(size_t)(m0 + lr) * DDIM + k0 + lc];
    float4 wv = *(const float4*)&W[(size_t)(n0 + lr) * DDIM + k0 + lc];
    As[lc + 0][lr] = av.x; As[lc + 1][lr] = av.y;
    As[lc + 2][lr] = av.z; As[lc + 3][lr] = av.w;
    Ws[lc + 0][lr] = wv.x; Ws[lc + 1][lr] = wv.y;
    Ws[lc + 2][lr] = wv.z; Ws[lc + 3][lr] = wv.w;
    __syncthreads();
#pragma unroll
    for (int kk = 0; kk < 16; ++kk) {
      float4 a4 = *(const float4*)&As[kk][ty * 4];
      float4 b4 = *(const float4*)&Ws[kk][tx * 4];
      const float a[4] = {a4.x, a4.y, a4.z, a4.w};
      const float b[4] = {b4.x, b4.y, b4.z, b4.w};
#pragma unroll
      for (int r = 0; r < 4; ++r)
#pragma unroll
        for (int c = 0; c < 4; ++c)
          acc[r][c] = fmaf(a[r], b[c], acc[r][c]);
    }
  }
#pragma unroll
  for (int r = 0; r < 4; ++r) {
    float4 o;
    o.x = acc[r][0] + bv.x;
    o.y = acc[r][1] + bv.y;
    o.z = acc[r][2] + bv.z;
    o.w = acc[r][3] + bv.w;
    *(float4*)&out[(size_t)(m0 + ty * 4 + r) * DDIM + nb] = o;
  }
}

// ---------- launcher ----------
extern "C" void kernel_launch(void* const* d_in, const int* in_sizes, int n_in,
                              void* d_out, int out_size, void* d_ws,
                              size_t ws_size, hipStream_t stream) {
  const float* x = (const float*)d_in[0];
  const float* Wq = (const float*)d_in[1];
  const float* bq = (const float*)d_in[2];
  const float* Wk = (const float*)d_in[3];
  const float* bk = (const float*)d_in[4];
  const float* Wv = (const float*)d_in[5];
  const float* bv = (const float*)d_in[6];
  const float* Wo = (const float*)d_in[7];
  const float* bo = (const float*)d_in[8];

  float* out = (float*)d_out;
  float* attSum = out + (size_t)MROWS * DDIM;
  float* attMask = attSum + (size_t)NB * SDIM * SDIM;

  char* ws = (char*)d_ws;
  const size_t bigF = (size_t)MROWS * DDIM * sizeof(float);    // 16.78 MB
  const size_t bigH = (size_t)MROWS * DDIM * sizeof(_Float16); // 8.39 MB
  const size_t wH = (size_t)DDIM * DDIM * sizeof(_Float16);    // 2.10 MB
  _Float16* Qh = (_Float16*)ws;  ws += bigH;
  _Float16* Kh = (_Float16*)ws;  ws += bigH;
  float* V = (float*)ws;         ws += bigF;
  float* merged = (float*)ws;    ws += bigF;
  _Float16* xh = (_Float16*)ws;  ws += bigH;
  _Float16* Wqh = (_Float16*)ws; ws += wH;
  _Float16* Wkh = (_Float16*)ws; ws += wH;
  _Float16* Wvh = (_Float16*)ws; ws += wH;
  float* invDen = (float*)ws;    ws += (size_t)NB * NH * SDIM * sizeof(float);
  float4* ev = (float4*)ws;      ws += (size_t)MAXEV * sizeof(float4);
  int* flags = (int*)ws;         ws += (size_t)MROWS * sizeof(int);
  int* ecnt = (int*)ws;          ws += 16;

  hipMemsetAsync(merged, 0, bigF, stream);
  hipMemsetAsync(flags, 0, (size_t)MROWS * sizeof(int), stream);
  hipMemsetAsync(ecnt, 0, 16, stream);

  dim3 blk(256);
  cvt_f16<<<dim3(7168), blk, 0, stream>>>(x, Wq, Wk, Wv, xh, Wqh, Wkh, Wvh);
  proj_gemm<<<dim3(8, 32, 3), blk, 0, stream>>>(xh, Wqh, Wkh, Wvh, bq, bk, bv,
                                                Qh, Kh, V);
  attn_denom<<<dim3(32, 32), blk, 0, stream>>>(Qh, Kh, invDen);
  attn_pass2<<<dim3(32, 32, 2), blk, 0, stream>>>(Qh, Kh, invDen, attSum,
                                                  attMask, ev, ecnt);
  apply_events<<<dim3(256), dim3(64), 0, stream>>>(ev, ecnt, V, merged, flags);
  out_gemm<<<dim3(16, 64), blk, 0, stream>>>(merged, Wo, bo, out, flags);
}